// Round 1
// 6797.528 us; speedup vs baseline: 1.0865x; 1.0865x over previous
//
#include <hip/hip_runtime.h>
#include <cmath>

#define DIM 768
#define DEPTH 8
#define HEADS 12
#define DH 64
#define DFF 2048
#define NTOK 16384   // B*T*S = 2*32*256
#define BB 2
#define TT 32
#define SS 256

typedef __attribute__((ext_vector_type(8))) short short8;
typedef __attribute__((ext_vector_type(4))) float f32x4;

__device__ __forceinline__ float sigmoidf_(float x) { return 1.0f / (1.0f + __expf(-x)); }
__device__ __forceinline__ float geluf_(float x) {
  return 0.5f * x * (1.0f + erff(x * 0.70710678118654752f));
}
__device__ __forceinline__ unsigned short f2bf(float x) {
  union { float f; unsigned int u; } a; a.f = x;
  unsigned int r = a.u + 0x7fff + ((a.u >> 16) & 1);   // RNE
  return (unsigned short)(r >> 16);
}
__device__ __forceinline__ float bf2f(unsigned short h) {
  union { unsigned int u; float f; } a; a.u = ((unsigned int)h) << 16;
  return a.f;
}
__device__ __forceinline__ void load_lds16(const void* g, void* l) {
  __builtin_amdgcn_global_load_lds(
      (const __attribute__((address_space(1))) unsigned int*)g,
      (__attribute__((address_space(3))) unsigned int*)l, 16, 0, 0);
}

// ---------------- RMSNorm: one block per row of 768 ----------------
template<int BF>
__global__ __launch_bounds__(256) void rmsnorm_kernel(
    const float* __restrict__ x, const float* __restrict__ w, void* __restrict__ outp)
{
  int row = blockIdx.x;
  int tid = threadIdx.x;
  const float* xr = x + (size_t)row * DIM;
  float v0 = xr[tid], v1 = xr[tid + 256], v2 = xr[tid + 512];
  float ss = v0 * v0 + v1 * v1 + v2 * v2;
  #pragma unroll
  for (int off = 32; off; off >>= 1) ss += __shfl_xor(ss, off);
  __shared__ float sred[4];
  if ((tid & 63) == 0) sred[tid >> 6] = ss;
  __syncthreads();
  float tot = sred[0] + sred[1] + sred[2] + sred[3];
  float r = rsqrtf(tot * (1.0f / DIM) + 1e-6f);
  if (BF) {
    unsigned short* orow = (unsigned short*)outp + (size_t)row * DIM;
    orow[tid]       = f2bf(v0 * r * w[tid]);
    orow[tid + 256] = f2bf(v1 * r * w[tid + 256]);
    orow[tid + 512] = f2bf(v2 * r * w[tid + 512]);
  } else {
    float* orow = (float*)outp + (size_t)row * DIM;
    orow[tid]       = v0 * r * w[tid];
    orow[tid + 256] = v1 * r * w[tid + 256];
    orow[tid + 512] = v2 * r * w[tid + 512];
  }
}

// ---------------- weight convert+transpose: W[K][N] f32 -> WT[N][K] bf16 ----------------
__global__ __launch_bounds__(256) void w_to_bt(
    const float* __restrict__ W, unsigned short* __restrict__ WT, int K, int N)
{
  __shared__ float t[32][33];
  int n0 = blockIdx.x * 32, k0 = blockIdx.y * 32;
  int c = threadIdx.x & 31, r8 = threadIdx.x >> 5;
  #pragma unroll
  for (int rr = r8; rr < 32; rr += 8)
    t[rr][c] = W[(size_t)(k0 + rr) * N + n0 + c];
  __syncthreads();
  #pragma unroll
  for (int rn = r8; rn < 32; rn += 8)
    WT[(size_t)(n0 + rn) * K + k0 + c] = f2bf(t[c][rn]);
}

// ---------------- bf16 MFMA GEMM: 128x128 tile, BK=32 (m97 structure) ----------------
// A: MxK bf16 row-major. BT: NxK bf16 row-major (= B transposed).
// MODE 0: Cf = A@B (+bias)            (fp32 out)
// MODE 1: Cf += A@B (+bias)           (fp32 accumulate)
// MODE 2: Hg = bf16(A@B + bias)       (bf16 out)
// MODE 3: Hg = bf16(Hg * gelu(A@B + bias))
template<int MODE>
__global__ __launch_bounds__(256) void gemm_bf16(
    const unsigned short* __restrict__ A, const unsigned short* __restrict__ BT,
    float* __restrict__ Cf, unsigned short* __restrict__ Hg,
    const float* __restrict__ bias, int M, int N, int K)
{
  __shared__ unsigned short As[128 * 32];
  __shared__ unsigned short Bs[128 * 32];
  const int tid = threadIdx.x;
  const int wave = tid >> 6;
  const int lane = tid & 63;
  const int bm = blockIdx.y * 128;
  const int bn = blockIdx.x * 128;
  const int wm = (wave & 1) * 64;
  const int wn = (wave >> 1) * 64;

  f32x4 acc[4][4];
  #pragma unroll
  for (int i = 0; i < 4; ++i)
    #pragma unroll
    for (int j = 0; j < 4; ++j) acc[i][j] = (f32x4){0.f, 0.f, 0.f, 0.f};

  // staging: wave w loads rows [32w, 32w+32) of each tile, 2 insts x 16 rows
  const int srow = wave * 32 + (lane >> 2);
  const int skoff = (lane & 3) * 8;            // ushorts (16 B)
  const unsigned short* gA = A + (size_t)(bm + srow) * K + skoff;
  const unsigned short* gB = BT + (size_t)(bn + srow) * K + skoff;
  unsigned short* lA = &As[(wave * 32) * 32];
  unsigned short* lB = &Bs[(wave * 32) * 32];

  const int fr = lane & 15;
  const int fq = (lane >> 4) * 8;

  for (int k0 = 0; k0 < K; k0 += 32) {
    load_lds16(gA + k0, lA);
    load_lds16(gA + k0 + 16 * K, lA + 16 * 32);
    load_lds16(gB + k0, lB);
    load_lds16(gB + k0 + 16 * K, lB + 16 * 32);
    __syncthreads();
    short8 a[4], b[4];
    #pragma unroll
    for (int i = 0; i < 4; ++i)
      a[i] = *(const short8*)&As[(wm + 16 * i + fr) * 32 + fq];
    #pragma unroll
    for (int j = 0; j < 4; ++j)
      b[j] = *(const short8*)&Bs[(wn + 16 * j + fr) * 32 + fq];
    #pragma unroll
    for (int i = 0; i < 4; ++i)
      #pragma unroll
      for (int j = 0; j < 4; ++j)
        acc[i][j] = __builtin_amdgcn_mfma_f32_16x16x32_bf16(a[i], b[j], acc[i][j], 0, 0, 0);
    __syncthreads();
  }

  // epilogue: C[row=(lane>>4)*4+r + 16i][col=(lane&15) + 16j]
  const int crow0 = bm + wm + (lane >> 4) * 4;
  const int ccol0 = bn + wn + fr;
  float bv[4];
  #pragma unroll
  for (int j = 0; j < 4; ++j) bv[j] = bias ? bias[ccol0 + 16 * j] : 0.0f;
  #pragma unroll
  for (int i = 0; i < 4; ++i) {
    #pragma unroll
    for (int r = 0; r < 4; ++r) {
      int row = crow0 + 16 * i + r;
      #pragma unroll
      for (int j = 0; j < 4; ++j) {
        int col = ccol0 + 16 * j;
        size_t idx = (size_t)row * N + col;
        float val = acc[i][j][r] + bv[j];
        if (MODE == 0) Cf[idx] = val;
        else if (MODE == 1) Cf[idx] += val;
        else if (MODE == 2) Hg[idx] = f2bf(val);
        else Hg[idx] = f2bf(bf2f(Hg[idx]) * geluf_(val));
      }
    }
  }
}

// ---------------- N=12 projection + sigmoid (mix / gates), bf16 A ----------------
__global__ __launch_bounds__(256) void proj12_kernel(
    const unsigned short* __restrict__ A, const float* __restrict__ Bw,
    const float* __restrict__ bias, float* __restrict__ out)
{
  int row = blockIdx.x * 4 + (threadIdx.x >> 6);
  int lane = threadIdx.x & 63;
  const unsigned short* ar = A + (size_t)row * DIM;
  float acc[HEADS];
  #pragma unroll
  for (int j = 0; j < HEADS; ++j) acc[j] = 0.0f;
  for (int k2 = lane; k2 < DIM; k2 += 64) {
    float a = bf2f(ar[k2]);
    const float* bw = Bw + (size_t)k2 * HEADS;
    #pragma unroll
    for (int j = 0; j < HEADS; ++j) acc[j] = fmaf(a, bw[j], acc[j]);
  }
  #pragma unroll
  for (int j = 0; j < HEADS; ++j) {
    #pragma unroll
    for (int off = 32; off; off >>= 1) acc[j] += __shfl_xor(acc[j], off);
  }
  if (lane < HEADS) {
    float r = acc[lane] + (bias ? bias[lane] : 0.0f);
    out[(size_t)row * HEADS + lane] = sigmoidf_(r);
  }
}

// ---------------- qkv postprocess: v-lerp, k-norm+gamma, rotary ----------------
// one block per token, one wave (64 lanes) per head
__global__ __launch_bounds__(768) void qkv_fix_kernel(
    float* __restrict__ q, float* __restrict__ k, float* __restrict__ v,
    const float* __restrict__ rv, const float* __restrict__ mix,
    const float* __restrict__ kgam, int is_time)
{
  int tok = blockIdx.x;
  int h = threadIdx.x >> 6;
  int d = threadIdx.x & 63;
  size_t idx = (size_t)tok * DIM + h * DH + d;
  float kv = k[idx];
  float ss = kv * kv;
  #pragma unroll
  for (int off = 32; off; off >>= 1) ss += __shfl_xor(ss, off);
  float nrm = fmaxf(sqrtf(ss), 1e-12f);
  kv = kv / nrm * (kgam[h * DH + d] + 1.0f) * 8.0f;   // sqrt(DH)=8
  float mv = mix[(size_t)tok * HEADS + h];
  float vv = v[idx];
  v[idx] = vv + mv * (rv[idx] - vv);
  float qv = q[idx];
  if (is_time) {
    int t = (tok >> 8) & 31;          // token = (b*32+t)*256+s
    int j = d & 31;
    float ang = (float)t * __expf(-(float)j * (9.210340371976184f / 32.0f));
    float cs = cosf(ang), sn = sinf(ang);
    float qp = __shfl_xor(qv, 32);
    float kp = __shfl_xor(kv, 32);
    float sgn = (d < 32) ? -1.0f : 1.0f;
    qv = qv * cs + sgn * qp * sn;
    kv = kv * cs + sgn * kp * sn;
  }
  q[idx] = qv;
  k[idx] = kv;
}

// ---------------- MFMA space attention: one block per (seq, head), n=256 ----------------
// S = QK^T/8, softclamped (50*tanh(s/50)), direct exp (no max: scores bounded by +-50),
// P rounded to bf16 (numerator+denominator consistent), PV via MFMA.
// Fragment layouts (16x16x32 bf16, verified in gemm_bf16 above):
//   A: lane holds A[row=lane&15][k=(lane>>4)*8+i]
//   B: lane holds B[k=(lane>>4)*8+i][col=lane&15]
//   C: lane holds C[row=(lane>>4)*4+r][col=lane&15]
__global__ __launch_bounds__(256, 2) void attn_mfma_kernel(
    const float* __restrict__ q, const float* __restrict__ k,
    const float* __restrict__ v, const float* __restrict__ gate,
    unsigned short* __restrict__ o)
{
  // swizzled LDS: Ks[row][64] (8x16B units/row, u^=row&7),
  // VsT[d][128] (16 units/row, u^=d&15), Pw per-wave [64][64] (u^=row&7)
  __shared__ __align__(16) unsigned short Ks[128 * 64];
  __shared__ __align__(16) unsigned short VsT[64 * 128];
  __shared__ __align__(16) unsigned short Pw[4][64 * 64];
  const int tid = threadIdx.x;
  const int wave = tid >> 6;
  const int lane = tid & 63;
  const int g = lane >> 4;
  const int c16 = lane & 15;
  const int bp = blockIdx.x;
  const int h = blockIdx.y;
  const size_t qoff = (size_t)bp * SS * DIM + h * DH;

  // Q fragments: wave owns rows [64*wave, 64*wave+64)
  short8 aq[4][2];
  #pragma unroll
  for (int i = 0; i < 4; ++i) {
    const float* qp = q + qoff + (size_t)(wave * 64 + i * 16 + c16) * DIM;
    #pragma unroll
    for (int cc = 0; cc < 2; ++cc) {
      float4 f0 = *(const float4*)(qp + cc * 32 + g * 8);
      float4 f1 = *(const float4*)(qp + cc * 32 + g * 8 + 4);
      short8 t;
      t[0] = (short)f2bf(f0.x); t[1] = (short)f2bf(f0.y);
      t[2] = (short)f2bf(f0.z); t[3] = (short)f2bf(f0.w);
      t[4] = (short)f2bf(f1.x); t[5] = (short)f2bf(f1.y);
      t[6] = (short)f2bf(f1.z); t[7] = (short)f2bf(f1.w);
      aq[i][cc] = t;
    }
  }

  f32x4 oacc[4][4];
  float rs[4][4];
  #pragma unroll
  for (int i = 0; i < 4; ++i)
    #pragma unroll
    for (int j = 0; j < 4; ++j) {
      oacc[i][j] = (f32x4){0.f, 0.f, 0.f, 0.f};
      rs[i][j] = 0.f;
    }

  for (int half = 0; half < 2; ++half) {
    const int r0 = half * 128;
    // stage K rows [r0, r0+128): 1024 16B units, coalesced reads
    #pragma unroll
    for (int it = 0; it < 4; ++it) {
      int f = tid + it * 256;
      int row = f >> 3, u = f & 7;
      const float* kp = k + qoff + (size_t)(r0 + row) * DIM + u * 8;
      float4 f0 = *(const float4*)kp;
      float4 f1 = *(const float4*)(kp + 4);
      short8 t;
      t[0] = (short)f2bf(f0.x); t[1] = (short)f2bf(f0.y);
      t[2] = (short)f2bf(f0.z); t[3] = (short)f2bf(f0.w);
      t[4] = (short)f2bf(f1.x); t[5] = (short)f2bf(f1.y);
      t[6] = (short)f2bf(f1.z); t[7] = (short)f2bf(f1.w);
      *(short8*)&Ks[row * 64 + ((u ^ (row & 7)) << 3)] = t;
    }
    // stage V transposed: VsT[d][j], j local in [0,128)
    #pragma unroll
    for (int it = 0; it < 8; ++it) {
      int f = tid + it * 256;
      int j = f & 127, dq = f >> 7;
      float4 f0 = *(const float4*)(v + qoff + (size_t)(r0 + j) * DIM + dq * 4);
      int u = j >> 3;
      #pragma unroll
      for (int c = 0; c < 4; ++c) {
        int d = dq * 4 + c;
        float val = (c == 0) ? f0.x : (c == 1) ? f0.y : (c == 2) ? f0.z : f0.w;
        VsT[d * 128 + ((u ^ (d & 15)) << 3) + (j & 7)] = f2bf(val);
      }
    }
    __syncthreads();

    #pragma unroll
    for (int jc = 0; jc < 2; ++jc) {
      const int lr0 = jc * 64;
      // ---- S = Q K^T for 64 q-rows x 64 k-cols ----
      f32x4 s[4][4];
      #pragma unroll
      for (int i = 0; i < 4; ++i)
        #pragma unroll
        for (int j = 0; j < 4; ++j) s[i][j] = (f32x4){0.f, 0.f, 0.f, 0.f};
      #pragma unroll
      for (int jt = 0; jt < 4; ++jt) {
        int row = lr0 + jt * 16 + c16;
        short8 b0 = *(const short8*)&Ks[row * 64 + ((g ^ (row & 7)) << 3)];
        short8 b1 = *(const short8*)&Ks[row * 64 + (((4 + g) ^ (row & 7)) << 3)];
        #pragma unroll
        for (int i = 0; i < 4; ++i) {
          s[i][jt] = __builtin_amdgcn_mfma_f32_16x16x32_bf16(aq[i][0], b0, s[i][jt], 0, 0, 0);
          s[i][jt] = __builtin_amdgcn_mfma_f32_16x16x32_bf16(aq[i][1], b1, s[i][jt], 0, 0, 0);
        }
      }
      // ---- softclamp + exp; write bf16 P to wave-private LDS ----
      // p = exp(50*tanh(sv/50)), tanh(x) = 1 - 2/(e^{2x}+1), e^{2x} = exp2(sv*log2e/25)
      #pragma unroll
      for (int i = 0; i < 4; ++i) {
        #pragma unroll
        for (int jt = 0; jt < 4; ++jt) {
          int pj = jt * 16 + c16;
          int uj = pj >> 3;
          #pragma unroll
          for (int r = 0; r < 4; ++r) {
            float sv = s[i][jt][r] * 0.125f;
            float a = exp2f(sv * 0.057707802f);
            float rc = __builtin_amdgcn_rcpf(a + 1.0f);
            float p = exp2f(fmaf(-144.26950408f, rc, 72.13475204f));
            unsigned short pb = f2bf(p);
            rs[i][r] += bf2f(pb);
            int prow = i * 16 + g * 4 + r;
            Pw[wave][prow * 64 + ((uj ^ (prow & 7)) << 3) + (pj & 7)] = pb;
          }
        }
      }
      // ---- O += P V ----
      #pragma unroll
      for (int jj = 0; jj < 2; ++jj) {
        short8 pa[4];
        #pragma unroll
        for (int i = 0; i < 4; ++i) {
          int prow = i * 16 + c16;
          int u = jj * 4 + g;
          pa[i] = *(const short8*)&Pw[wave][prow * 64 + ((u ^ (prow & 7)) << 3)];
        }
        const int jl = lr0 + jj * 32 + g * 8;
        const int uv = jl >> 3;
        #pragma unroll
        for (int dt = 0; dt < 4; ++dt) {
          int d = dt * 16 + c16;
          short8 bv = *(const short8*)&VsT[d * 128 + ((uv ^ (d & 15)) << 3)];
          #pragma unroll
          for (int i = 0; i < 4; ++i)
            oacc[i][dt] = __builtin_amdgcn_mfma_f32_16x16x32_bf16(pa[i], bv, oacc[i][dt], 0, 0, 0);
        }
      }
    }
    __syncthreads();
  }

  // row-sum reduce across the 16 lanes sharing g (cols live in lane&15)
  #pragma unroll
  for (int i = 0; i < 4; ++i)
    #pragma unroll
    for (int r = 0; r < 4; ++r) {
      float t = rs[i][r];
      t += __shfl_xor(t, 1); t += __shfl_xor(t, 2);
      t += __shfl_xor(t, 4); t += __shfl_xor(t, 8);
      rs[i][r] = t;
    }
  // write: O[row][d] * gate/sum, row = 64w+16i+4g+r, d = 16dt+c16
  #pragma unroll
  for (int i = 0; i < 4; ++i) {
    #pragma unroll
    for (int r = 0; r < 4; ++r) {
      int row = wave * 64 + i * 16 + g * 4 + r;
      int tq = bp * SS + row;
      float gt = gate[(size_t)tq * HEADS + h] / rs[i][r];
      unsigned short* op = o + (size_t)tq * DIM + h * DH;
      #pragma unroll
      for (int dt = 0; dt < 4; ++dt)
        op[dt * 16 + c16] = f2bf(oacc[i][dt][r] * gt);
    }
  }
}

// ---------------- scalar attention (kept for time layers, n=32 causal) ----------------
#define ACHUNK 128
__global__ __launch_bounds__(256) void attn_kernel(
    const float* __restrict__ q, const float* __restrict__ k,
    const float* __restrict__ v, const float* __restrict__ gate,
    unsigned short* __restrict__ o, int n, int ln, int is_time)
{
  __shared__ __align__(16) float Ks[ACHUNK][DH];
  __shared__ __align__(16) float Vs[ACHUNK][DH];
  const int tid = threadIdx.x;
  const int h = blockIdx.y;
  const int G = 256 >> ln;
  const int g = tid >> ln;
  const int qi = tid & (n - 1);
  const int bp0 = blockIdx.x * G;
  const int step = is_time ? SS : 1;

  int bp = bp0 + g;
  int base = is_time ? ((bp >> 8) * (TT * SS) + (bp & 255)) : bp * SS;
  int tq = base + qi * step;

  float4 q4[16];
  const float4* qp = (const float4*)(q + (size_t)tq * DIM + h * DH);
  #pragma unroll
  for (int c = 0; c < 16; ++c) q4[c] = qp[c];

  float4 o4[16];
  #pragma unroll
  for (int c = 0; c < 16; ++c) o4[c] = make_float4(0.f, 0.f, 0.f, 0.f);
  float sum = 0.0f;

  for (int r0 = 0; r0 < 256; r0 += ACHUNK) {
    #pragma unroll
    for (int w = 0; w < ACHUNK * (DH / 4) / 256; ++w) {
      int f = tid + w * 256;
      int r = f >> 4;
      int c4 = f & 15;
      int rr = r0 + r;
      int gg = rr >> ln;
      int jj = rr & (n - 1);
      int bpr = bp0 + gg;
      int baser = is_time ? ((bpr >> 8) * (TT * SS) + (bpr & 255)) : bpr * SS;
      int tok = baser + jj * step;
      size_t off = (size_t)tok * DIM + h * DH;
      *(float4*)&Ks[r][c4 * 4] = ((const float4*)(k + off))[c4];
      *(float4*)&Vs[r][c4 * 4] = ((const float4*)(v + off))[c4];
    }
    __syncthreads();

    int lo = max(r0, g * n);
    int hi = min(r0 + ACHUNK, (g + 1) * n);
    for (int r = lo; r < hi; ++r) {
      int j = r - g * n;
      if (is_time && j > qi) break;
      int lr = r - r0;
      const float4* kr = (const float4*)&Ks[lr][0];
      float s = 0.0f;
      #pragma unroll
      for (int c = 0; c < 16; ++c) {
        float4 kk = kr[c];
        s += q4[c].x * kk.x + q4[c].y * kk.y + q4[c].z * kk.z + q4[c].w * kk.w;
      }
      s *= 0.125f;
      s = tanhf(s * 0.02f) * 50.0f;
      float p = __expf(s);
      sum += p;
      const float4* vr = (const float4*)&Vs[lr][0];
      #pragma unroll
      for (int c = 0; c < 16; ++c) {
        float4 vv = vr[c];
        o4[c].x += p * vv.x; o4[c].y += p * vv.y;
        o4[c].z += p * vv.z; o4[c].w += p * vv.w;
      }
    }
    __syncthreads();
  }

  float gt = gate[(size_t)tq * HEADS + h] / sum;
  unsigned short* op = o + (size_t)tq * DIM + h * DH;
  #pragma unroll
  for (int c = 0; c < 16; ++c) {
    ushort4 w;
    w.x = f2bf(o4[c].x * gt); w.y = f2bf(o4[c].y * gt);
    w.z = f2bf(o4[c].z * gt); w.w = f2bf(o4[c].w * gt);
    *(ushort4*)&op[c * 4] = w;
  }
}

// ---------------- driver ----------------
extern "C" void kernel_launch(void* const* d_in, const int* in_sizes, int n_in,
                              void* d_out, int out_size, void* d_ws, size_t ws_size,
                              hipStream_t stream)
{
  const float* tokens = (const float*)d_in[0];
  const float* attn_norm_w = (const float*)d_in[1];
  const float* Wq   = (const float*)d_in[2];
  const float* Wk   = (const float*)d_in[3];
  const float* Wv   = (const float*)d_in[4];
  const float* Wo   = (const float*)d_in[5];
  const float* Wg   = (const float*)d_in[6];
  const float* Wmix = (const float*)d_in[7];
  const float* bmix = (const float*)d_in[8];
  const float* kgam = (const float*)d_in[9];
  const float* ffw  = (const float*)d_in[10];
  const float* Win  = (const float*)d_in[11];
  const float* bin  = (const float*)d_in[12];
  const float* Wout = (const float*)d_in[13];
  const float* bout = (const float*)d_in[14];
  const float* vrw  = (const float*)d_in[15];
  const float* vrW  = (const float*)d_in[16];
  const float* fnw  = (const float*)d_in[17];

  const size_t NT = (size_t)NTOK * DIM;   // 12,582,912
  float* ws  = (float*)d_ws;
  float* x   = ws;                        // NT f32
  float* q   = x  + NT;                   // NT f32
  float* k   = q  + NT;                   // NT f32
  float* v   = k  + NT;                   // NT f32
  float* rv  = v  + NT;                   // NT f32
  float* mix = rv + NT;                   // NTOK*12
  float* gate = mix + (size_t)NTOK * HEADS;
  unsigned short* tn   = (unsigned short*)(gate + (size_t)NTOK * HEADS); // NT bf16
  unsigned short* wqT  = tn + NT;                    // per-layer bf16 weights
  unsigned short* wkT  = wqT + 768 * 768;
  unsigned short* wvT  = wkT + 768 * 768;
  unsigned short* woT  = wvT + 768 * 768;
  unsigned short* winT = woT + 768 * 768;            // 4096*768
  unsigned short* woutT= winT + (size_t)4096 * 768;  // 768*2048
  unsigned short* vrWT = woutT + (size_t)768 * 2048; // 768*768
  unsigned short* hg   = (unsigned short*)q;         // 16384*2048 bf16, aliases q+k

  hipMemcpyAsync(x, tokens, NT * sizeof(float), hipMemcpyDeviceToDevice, stream);

  // value residual: rv = rmsnorm(tokens, vrw) @ vrW
  w_to_bt<<<dim3(24, 24), 256, 0, stream>>>(vrW, vrWT, DIM, DIM);
  rmsnorm_kernel<1><<<NTOK, 256, 0, stream>>>(tokens, vrw, tn);
  gemm_bf16<0><<<dim3(6, 128), 256, 0, stream>>>(
      tn, vrWT, rv, nullptr, nullptr, NTOK, DIM, DIM);

  for (int i = 0; i < DEPTH; ++i) {
    int is_time = ((i + 1) % 4 == 0) ? 1 : 0;
    // per-layer weight conversion (bf16, transposed)
    w_to_bt<<<dim3(24, 24), 256, 0, stream>>>(Wq + (size_t)i * DIM * DIM, wqT, DIM, DIM);
    w_to_bt<<<dim3(24, 24), 256, 0, stream>>>(Wk + (size_t)i * DIM * DIM, wkT, DIM, DIM);
    w_to_bt<<<dim3(24, 24), 256, 0, stream>>>(Wv + (size_t)i * DIM * DIM, wvT, DIM, DIM);
    w_to_bt<<<dim3(24, 24), 256, 0, stream>>>(Wo + (size_t)i * DIM * DIM, woT, DIM, DIM);
    w_to_bt<<<dim3(128, 24), 256, 0, stream>>>(Win + (size_t)i * DIM * 2 * DFF, winT, DIM, 2 * DFF);
    w_to_bt<<<dim3(24, 64), 256, 0, stream>>>(Wout + (size_t)i * DFF * DIM, woutT, DFF, DIM);

    rmsnorm_kernel<1><<<NTOK, 256, 0, stream>>>(x, attn_norm_w + (size_t)i * DIM, tn);
    gemm_bf16<0><<<dim3(6, 128), 256, 0, stream>>>(tn, wqT, q, nullptr, nullptr, NTOK, DIM, DIM);
    gemm_bf16<0><<<dim3(6, 128), 256, 0, stream>>>(tn, wkT, k, nullptr, nullptr, NTOK, DIM, DIM);
    gemm_bf16<0><<<dim3(6, 128), 256, 0, stream>>>(tn, wvT, v, nullptr, nullptr, NTOK, DIM, DIM);
    proj12_kernel<<<NTOK / 4, 256, 0, stream>>>(
        tn, Wmix + (size_t)i * DIM * HEADS, bmix + (size_t)i * HEADS, mix);
    proj12_kernel<<<NTOK / 4, 256, 0, stream>>>(
        tn, Wg + (size_t)i * DIM * HEADS, nullptr, gate);
    qkv_fix_kernel<<<dim3(NTOK), 768, 0, stream>>>(
        q, k, v, rv, mix, kgam + (size_t)i * HEADS * DH, is_time);
    if (is_time)
      attn_kernel<<<dim3((BB * SS) / 8, HEADS), 256, 0, stream>>>(
          q, k, v, gate, tn, TT, 5, 1);
    else
      attn_mfma_kernel<<<dim3(BB * TT, HEADS), 256, 0, stream>>>(
          q, k, v, gate, tn);
    gemm_bf16<1><<<dim3(6, 128), 256, 0, stream>>>(tn, woT, x, nullptr, nullptr, NTOK, DIM, DIM);
    // FF
    rmsnorm_kernel<1><<<NTOK, 256, 0, stream>>>(x, ffw + (size_t)i * DIM, tn);
    gemm_bf16<2><<<dim3(16, 128), 256, 0, stream>>>(
        tn, winT, nullptr, hg, bin + (size_t)i * 2 * DFF, NTOK, DFF, DIM);
    gemm_bf16<3><<<dim3(16, 128), 256, 0, stream>>>(
        tn, winT + (size_t)DFF * DIM, nullptr, hg, bin + (size_t)i * 2 * DFF + DFF,
        NTOK, DFF, DIM);
    gemm_bf16<1><<<dim3(6, 128), 256, 0, stream>>>(
        hg, woutT, x, nullptr, bout + (size_t)i * DIM, NTOK, DIM, DFF);
  }
  rmsnorm_kernel<0><<<NTOK, 256, 0, stream>>>(x, fnw, (float*)d_out);
}

// Round 2
// 6264.557 us; speedup vs baseline: 1.1790x; 1.0851x over previous
//
#include <hip/hip_runtime.h>
#include <cmath>

#define DIM 768
#define DEPTH 8
#define HEADS 12
#define DH 64
#define DFF 2048
#define NTOK 16384   // B*T*S = 2*32*256
#define BB 2
#define TT 32
#define SS 256

typedef __attribute__((ext_vector_type(8))) short short8;
typedef __attribute__((ext_vector_type(4))) float f32x4;

__device__ __forceinline__ float sigmoidf_(float x) { return 1.0f / (1.0f + __expf(-x)); }
__device__ __forceinline__ float geluf_(float x) {
  return 0.5f * x * (1.0f + erff(x * 0.70710678118654752f));
}
__device__ __forceinline__ unsigned short f2bf(float x) {
  union { float f; unsigned int u; } a; a.f = x;
  unsigned int r = a.u + 0x7fff + ((a.u >> 16) & 1);   // RNE
  return (unsigned short)(r >> 16);
}
__device__ __forceinline__ float bf2f(unsigned short h) {
  union { unsigned int u; float f; } a; a.u = ((unsigned int)h) << 16;
  return a.f;
}
__device__ __forceinline__ void load_lds16(const void* g, void* l) {
  __builtin_amdgcn_global_load_lds(
      (const __attribute__((address_space(1))) unsigned int*)g,
      (__attribute__((address_space(3))) unsigned int*)l, 16, 0, 0);
}
// softclamp+exp: p = exp(50*tanh(sv/50)) = 2^72.1347 * 2^(-144.2695/(e^{sv/25}+1))
__device__ __forceinline__ float softclamp_exp(float sv) {
  float a = exp2f(sv * 0.057707802f);
  float rc = __builtin_amdgcn_rcpf(a + 1.0f);
  return exp2f(fmaf(-144.26950408f, rc, 72.13475204f));
}

// ---------------- RMSNorm: one block per row of 768 ----------------
template<int BF>
__global__ __launch_bounds__(256) void rmsnorm_kernel(
    const float* __restrict__ x, const float* __restrict__ w, void* __restrict__ outp)
{
  int row = blockIdx.x;
  int tid = threadIdx.x;
  const float* xr = x + (size_t)row * DIM;
  float v0 = xr[tid], v1 = xr[tid + 256], v2 = xr[tid + 512];
  float ss = v0 * v0 + v1 * v1 + v2 * v2;
  #pragma unroll
  for (int off = 32; off; off >>= 1) ss += __shfl_xor(ss, off);
  __shared__ float sred[4];
  if ((tid & 63) == 0) sred[tid >> 6] = ss;
  __syncthreads();
  float tot = sred[0] + sred[1] + sred[2] + sred[3];
  float r = rsqrtf(tot * (1.0f / DIM) + 1e-6f);
  if (BF) {
    unsigned short* orow = (unsigned short*)outp + (size_t)row * DIM;
    orow[tid]       = f2bf(v0 * r * w[tid]);
    orow[tid + 256] = f2bf(v1 * r * w[tid + 256]);
    orow[tid + 512] = f2bf(v2 * r * w[tid + 512]);
  } else {
    float* orow = (float*)outp + (size_t)row * DIM;
    orow[tid]       = v0 * r * w[tid];
    orow[tid + 256] = v1 * r * w[tid + 256];
    orow[tid + 512] = v2 * r * w[tid + 512];
  }
}

// ---------------- weight convert+transpose: W[K][N] f32 -> WT[N][K] bf16 ----------------
__global__ __launch_bounds__(256) void w_to_bt(
    const float* __restrict__ W, unsigned short* __restrict__ WT, int K, int N)
{
  __shared__ float t[32][33];
  int n0 = blockIdx.x * 32, k0 = blockIdx.y * 32;
  int c = threadIdx.x & 31, r8 = threadIdx.x >> 5;
  #pragma unroll
  for (int rr = r8; rr < 32; rr += 8)
    t[rr][c] = W[(size_t)(k0 + rr) * N + n0 + c];
  __syncthreads();
  #pragma unroll
  for (int rn = r8; rn < 32; rn += 8)
    WT[(size_t)(n0 + rn) * K + k0 + c] = f2bf(t[c][rn]);
}

// ---------------- bf16 MFMA GEMM: 128x128 tile, BK=32 (m97 structure) ----------------
// A: MxK bf16 row-major. BT: NxK bf16 row-major (= B transposed).
// MODE 0: Cf = A@B (+bias)            (fp32 out)
// MODE 1: Cf += A@B (+bias)           (fp32 accumulate)
// MODE 2: Hg = bf16(A@B + bias)       (bf16 out)
// MODE 3: Hg = bf16(Hg * gelu(A@B + bias))
template<int MODE>
__global__ __launch_bounds__(256) void gemm_bf16(
    const unsigned short* __restrict__ A, const unsigned short* __restrict__ BT,
    float* __restrict__ Cf, unsigned short* __restrict__ Hg,
    const float* __restrict__ bias, int M, int N, int K)
{
  __shared__ unsigned short As[128 * 32];
  __shared__ unsigned short Bs[128 * 32];
  const int tid = threadIdx.x;
  const int wave = tid >> 6;
  const int lane = tid & 63;
  const int bm = blockIdx.y * 128;
  const int bn = blockIdx.x * 128;
  const int wm = (wave & 1) * 64;
  const int wn = (wave >> 1) * 64;

  f32x4 acc[4][4];
  #pragma unroll
  for (int i = 0; i < 4; ++i)
    #pragma unroll
    for (int j = 0; j < 4; ++j) acc[i][j] = (f32x4){0.f, 0.f, 0.f, 0.f};

  const int srow = wave * 32 + (lane >> 2);
  const int skoff = (lane & 3) * 8;            // ushorts (16 B)
  const unsigned short* gA = A + (size_t)(bm + srow) * K + skoff;
  const unsigned short* gB = BT + (size_t)(bn + srow) * K + skoff;
  unsigned short* lA = &As[(wave * 32) * 32];
  unsigned short* lB = &Bs[(wave * 32) * 32];

  const int fr = lane & 15;
  const int fq = (lane >> 4) * 8;

  for (int k0 = 0; k0 < K; k0 += 32) {
    load_lds16(gA + k0, lA);
    load_lds16(gA + k0 + 16 * K, lA + 16 * 32);
    load_lds16(gB + k0, lB);
    load_lds16(gB + k0 + 16 * K, lB + 16 * 32);
    __syncthreads();
    short8 a[4], b[4];
    #pragma unroll
    for (int i = 0; i < 4; ++i)
      a[i] = *(const short8*)&As[(wm + 16 * i + fr) * 32 + fq];
    #pragma unroll
    for (int j = 0; j < 4; ++j)
      b[j] = *(const short8*)&Bs[(wn + 16 * j + fr) * 32 + fq];
    #pragma unroll
    for (int i = 0; i < 4; ++i)
      #pragma unroll
      for (int j = 0; j < 4; ++j)
        acc[i][j] = __builtin_amdgcn_mfma_f32_16x16x32_bf16(a[i], b[j], acc[i][j], 0, 0, 0);
    __syncthreads();
  }

  const int crow0 = bm + wm + (lane >> 4) * 4;
  const int ccol0 = bn + wn + fr;
  float bv[4];
  #pragma unroll
  for (int j = 0; j < 4; ++j) bv[j] = bias ? bias[ccol0 + 16 * j] : 0.0f;
  #pragma unroll
  for (int i = 0; i < 4; ++i) {
    #pragma unroll
    for (int r = 0; r < 4; ++r) {
      int row = crow0 + 16 * i + r;
      #pragma unroll
      for (int j = 0; j < 4; ++j) {
        int col = ccol0 + 16 * j;
        size_t idx = (size_t)row * N + col;
        float val = acc[i][j][r] + bv[j];
        if (MODE == 0) Cf[idx] = val;
        else if (MODE == 1) Cf[idx] += val;
        else if (MODE == 2) Hg[idx] = f2bf(val);
        else Hg[idx] = f2bf(bf2f(Hg[idx]) * geluf_(val));
      }
    }
  }
}

// ---------------- N=12 projection + sigmoid (mix / gates), bf16 A ----------------
__global__ __launch_bounds__(256) void proj12_kernel(
    const unsigned short* __restrict__ A, const float* __restrict__ Bw,
    const float* __restrict__ bias, float* __restrict__ out)
{
  int row = blockIdx.x * 4 + (threadIdx.x >> 6);
  int lane = threadIdx.x & 63;
  const unsigned short* ar = A + (size_t)row * DIM;
  float acc[HEADS];
  #pragma unroll
  for (int j = 0; j < HEADS; ++j) acc[j] = 0.0f;
  for (int k2 = lane; k2 < DIM; k2 += 64) {
    float a = bf2f(ar[k2]);
    const float* bw = Bw + (size_t)k2 * HEADS;
    #pragma unroll
    for (int j = 0; j < HEADS; ++j) acc[j] = fmaf(a, bw[j], acc[j]);
  }
  #pragma unroll
  for (int j = 0; j < HEADS; ++j) {
    #pragma unroll
    for (int off = 32; off; off >>= 1) acc[j] += __shfl_xor(acc[j], off);
  }
  if (lane < HEADS) {
    float r = acc[lane] + (bias ? bias[lane] : 0.0f);
    out[(size_t)row * HEADS + lane] = sigmoidf_(r);
  }
}

// ---------------- qkv postprocess: v-lerp, k-norm+gamma, rotary ----------------
__global__ __launch_bounds__(768) void qkv_fix_kernel(
    float* __restrict__ q, float* __restrict__ k, float* __restrict__ v,
    const float* __restrict__ rv, const float* __restrict__ mix,
    const float* __restrict__ kgam, int is_time)
{
  int tok = blockIdx.x;
  int h = threadIdx.x >> 6;
  int d = threadIdx.x & 63;
  size_t idx = (size_t)tok * DIM + h * DH + d;
  float kv = k[idx];
  float ss = kv * kv;
  #pragma unroll
  for (int off = 32; off; off >>= 1) ss += __shfl_xor(ss, off);
  float nrm = fmaxf(sqrtf(ss), 1e-12f);
  kv = kv / nrm * (kgam[h * DH + d] + 1.0f) * 8.0f;   // sqrt(DH)=8
  float mv = mix[(size_t)tok * HEADS + h];
  float vv = v[idx];
  v[idx] = vv + mv * (rv[idx] - vv);
  float qv = q[idx];
  if (is_time) {
    int t = (tok >> 8) & 31;          // token = (b*32+t)*256+s
    int j = d & 31;
    float ang = (float)t * __expf(-(float)j * (9.210340371976184f / 32.0f));
    float cs = cosf(ang), sn = sinf(ang);
    float qp = __shfl_xor(qv, 32);
    float kp = __shfl_xor(kv, 32);
    float sgn = (d < 32) ? -1.0f : 1.0f;
    qv = qv * cs + sgn * qp * sn;
    kv = kv * cs + sgn * kp * sn;
  }
  q[idx] = qv;
  k[idx] = kv;
}

// ---------------- MFMA space attention ----------------
// grid (BB*TT*2, HEADS): block = 128 q-rows of one (seq bp, head h); wave = 32 q-rows.
// S = QK^T/8, softclamped exp (no running max: scores bounded by +-50),
// P rounded to bf16 (numerator+denominator consistent), PV via MFMA.
// Fragment layouts (16x16x32 bf16): A: lane holds A[row=lane&15][k=(lane>>4)*8+i]
//   B: lane holds B[k=(lane>>4)*8+i][col=lane&15]; C: C[row=(lane>>4)*4+r][col=lane&15]
__global__ __launch_bounds__(256, 3) void attn_mfma_kernel(
    const float* __restrict__ q, const float* __restrict__ k,
    const float* __restrict__ v, const float* __restrict__ gate,
    unsigned short* __restrict__ o)
{
  __shared__ __align__(16) unsigned short Ks[128 * 64];    // 16 KB, u^=row&7
  __shared__ __align__(16) unsigned short VsT[64 * 128];   // 16 KB, u^=d&15
  __shared__ __align__(16) unsigned short Pw[4][32 * 64];  // 16 KB, u^=row&7
  const int tid = threadIdx.x;
  const int wave = tid >> 6;
  const int lane = tid & 63;
  const int g = lane >> 4;
  const int c16 = lane & 15;
  const int bp = blockIdx.x >> 1;
  const int qh = blockIdx.x & 1;
  const int h = blockIdx.y;
  const size_t qoff = (size_t)bp * SS * DIM + h * DH;
  const int qbase = qh * 128 + wave * 32;

  // Q fragments: wave owns rows [qbase, qbase+32)
  short8 aq[2][2];
  #pragma unroll
  for (int i = 0; i < 2; ++i) {
    const float* qp = q + qoff + (size_t)(qbase + i * 16 + c16) * DIM;
    #pragma unroll
    for (int cc = 0; cc < 2; ++cc) {
      float4 f0 = *(const float4*)(qp + cc * 32 + g * 8);
      float4 f1 = *(const float4*)(qp + cc * 32 + g * 8 + 4);
      short8 t;
      t[0] = (short)f2bf(f0.x); t[1] = (short)f2bf(f0.y);
      t[2] = (short)f2bf(f0.z); t[3] = (short)f2bf(f0.w);
      t[4] = (short)f2bf(f1.x); t[5] = (short)f2bf(f1.y);
      t[6] = (short)f2bf(f1.z); t[7] = (short)f2bf(f1.w);
      aq[i][cc] = t;
    }
  }

  f32x4 oacc[2][4];
  float rs[2][4];
  #pragma unroll
  for (int i = 0; i < 2; ++i)
    #pragma unroll
    for (int j = 0; j < 4; ++j) {
      oacc[i][j] = (f32x4){0.f, 0.f, 0.f, 0.f};
      rs[i][j] = 0.f;
    }

  for (int half = 0; half < 2; ++half) {
    const int r0 = half * 128;
    // stage K rows [r0, r0+128): coalesced
    #pragma unroll
    for (int it = 0; it < 4; ++it) {
      int f = tid + it * 256;
      int row = f >> 3, u = f & 7;
      const float* kp = k + qoff + (size_t)(r0 + row) * DIM + u * 8;
      float4 f0 = *(const float4*)kp;
      float4 f1 = *(const float4*)(kp + 4);
      short8 t;
      t[0] = (short)f2bf(f0.x); t[1] = (short)f2bf(f0.y);
      t[2] = (short)f2bf(f0.z); t[3] = (short)f2bf(f0.w);
      t[4] = (short)f2bf(f1.x); t[5] = (short)f2bf(f1.y);
      t[6] = (short)f2bf(f1.z); t[7] = (short)f2bf(f1.w);
      *(short8*)&Ks[row * 64 + ((u ^ (row & 7)) << 3)] = t;
    }
    // stage V transposed: VsT[d][j]
    #pragma unroll
    for (int it = 0; it < 8; ++it) {
      int f = tid + it * 256;
      int j = f & 127, dq = f >> 7;
      float4 f0 = *(const float4*)(v + qoff + (size_t)(r0 + j) * DIM + dq * 4);
      int u = j >> 3;
      #pragma unroll
      for (int c = 0; c < 4; ++c) {
        int d = dq * 4 + c;
        float val = (c == 0) ? f0.x : (c == 1) ? f0.y : (c == 2) ? f0.z : f0.w;
        VsT[d * 128 + ((u ^ (d & 15)) << 3) + (j & 7)] = f2bf(val);
      }
    }
    __syncthreads();

    #pragma unroll
    for (int jc = 0; jc < 2; ++jc) {
      const int lr0 = jc * 64;
      // ---- S = Q K^T for 32 q-rows x 64 k-cols ----
      f32x4 s[2][4];
      #pragma unroll
      for (int i = 0; i < 2; ++i)
        #pragma unroll
        for (int j = 0; j < 4; ++j) s[i][j] = (f32x4){0.f, 0.f, 0.f, 0.f};
      #pragma unroll
      for (int jt = 0; jt < 4; ++jt) {
        int row = lr0 + jt * 16 + c16;
        short8 b0 = *(const short8*)&Ks[row * 64 + ((g ^ (row & 7)) << 3)];
        short8 b1 = *(const short8*)&Ks[row * 64 + (((4 + g) ^ (row & 7)) << 3)];
        #pragma unroll
        for (int i = 0; i < 2; ++i) {
          s[i][jt] = __builtin_amdgcn_mfma_f32_16x16x32_bf16(aq[i][0], b0, s[i][jt], 0, 0, 0);
          s[i][jt] = __builtin_amdgcn_mfma_f32_16x16x32_bf16(aq[i][1], b1, s[i][jt], 0, 0, 0);
        }
      }
      // ---- softclamp + exp; bf16 P to wave-private LDS ----
      #pragma unroll
      for (int i = 0; i < 2; ++i) {
        #pragma unroll
        for (int jt = 0; jt < 4; ++jt) {
          int pj = jt * 16 + c16;
          int uj = pj >> 3;
          #pragma unroll
          for (int r = 0; r < 4; ++r) {
            float p = softclamp_exp(s[i][jt][r] * 0.125f);
            unsigned short pb = f2bf(p);
            rs[i][r] += bf2f(pb);
            int prow = i * 16 + g * 4 + r;
            Pw[wave][prow * 64 + ((uj ^ (prow & 7)) << 3) + (pj & 7)] = pb;
          }
        }
      }
      // ---- O += P V ----
      #pragma unroll
      for (int jj = 0; jj < 2; ++jj) {
        short8 pa[2];
        #pragma unroll
        for (int i = 0; i < 2; ++i) {
          int prow = i * 16 + c16;
          int u = jj * 4 + g;
          pa[i] = *(const short8*)&Pw[wave][prow * 64 + ((u ^ (prow & 7)) << 3)];
        }
        const int jl = lr0 + jj * 32 + g * 8;
        const int uv = jl >> 3;
        #pragma unroll
        for (int dt = 0; dt < 4; ++dt) {
          int d = dt * 16 + c16;
          short8 bv = *(const short8*)&VsT[d * 128 + ((uv ^ (d & 15)) << 3)];
          #pragma unroll
          for (int i = 0; i < 2; ++i)
            oacc[i][dt] = __builtin_amdgcn_mfma_f32_16x16x32_bf16(pa[i], bv, oacc[i][dt], 0, 0, 0);
        }
      }
    }
    __syncthreads();
  }

  // row-sum reduce across the 16 lanes sharing g
  #pragma unroll
  for (int i = 0; i < 2; ++i)
    #pragma unroll
    for (int r = 0; r < 4; ++r) {
      float t = rs[i][r];
      t += __shfl_xor(t, 1); t += __shfl_xor(t, 2);
      t += __shfl_xor(t, 4); t += __shfl_xor(t, 8);
      rs[i][r] = t;
    }
  #pragma unroll
  for (int i = 0; i < 2; ++i) {
    #pragma unroll
    for (int r = 0; r < 4; ++r) {
      int row = qbase + i * 16 + g * 4 + r;
      int tq = bp * SS + row;
      float gt = gate[(size_t)tq * HEADS + h] / rs[i][r];
      unsigned short* op = o + (size_t)tq * DIM + h * DH;
      #pragma unroll
      for (int dt = 0; dt < 4; ++dt)
        op[dt * 16 + c16] = f2bf(oacc[i][dt][r] * gt);
    }
  }
}

// ---------------- MFMA time attention: wave = one (b,s) sequence, 32x32 causal ----------------
// grid (BB*SS/4, HEADS); token(t) = base + t*SS, base = b*TT*SS + s.
// K B-fragment addressing is identical to Q A-fragment (per-lane row c16, k-slice 8g).
__global__ __launch_bounds__(256, 3) void attn_time_mfma(
    const float* __restrict__ q, const float* __restrict__ k,
    const float* __restrict__ v, const float* __restrict__ gate,
    unsigned short* __restrict__ o)
{
  __shared__ __align__(16) unsigned short VT[4][64 * 32];  // [d][t'], u^=d&3, 4KB/wave
  __shared__ __align__(16) unsigned short Pw[4][32 * 32];  // [t][t'], u^=t&3, 2KB/wave
  const int tid = threadIdx.x;
  const int wave = tid >> 6;
  const int lane = tid & 63;
  const int g = lane >> 4;
  const int c16 = lane & 15;
  const int h = blockIdx.y;
  const int sp = blockIdx.x * 4 + wave;                 // 0..511
  const int base = (sp >> 8) * (TT * SS) + (sp & 255);  // b*8192 + s

  // Q and K fragments (rows t = 16i + c16, k-dim = d)
  short8 aq[2][2], bk[2][2];
  #pragma unroll
  for (int i = 0; i < 2; ++i) {
    const float* qp = q + (size_t)(base + (i * 16 + c16) * SS) * DIM + h * DH;
    const float* kp = k + (size_t)(base + (i * 16 + c16) * SS) * DIM + h * DH;
    #pragma unroll
    for (int cc = 0; cc < 2; ++cc) {
      float4 f0 = *(const float4*)(qp + cc * 32 + g * 8);
      float4 f1 = *(const float4*)(qp + cc * 32 + g * 8 + 4);
      short8 t;
      t[0] = (short)f2bf(f0.x); t[1] = (short)f2bf(f0.y);
      t[2] = (short)f2bf(f0.z); t[3] = (short)f2bf(f0.w);
      t[4] = (short)f2bf(f1.x); t[5] = (short)f2bf(f1.y);
      t[6] = (short)f2bf(f1.z); t[7] = (short)f2bf(f1.w);
      aq[i][cc] = t;
      float4 g0 = *(const float4*)(kp + cc * 32 + g * 8);
      float4 g1 = *(const float4*)(kp + cc * 32 + g * 8 + 4);
      short8 u;
      u[0] = (short)f2bf(g0.x); u[1] = (short)f2bf(g0.y);
      u[2] = (short)f2bf(g0.z); u[3] = (short)f2bf(g0.w);
      u[4] = (short)f2bf(g1.x); u[5] = (short)f2bf(g1.y);
      u[6] = (short)f2bf(g1.z); u[7] = (short)f2bf(g1.w);
      bk[i][cc] = u;
    }
  }

  // stage V transposed: lane handles t' = lane>>1, d-half = (lane&1)*32
  {
    int tp = lane >> 1;
    int dh0 = (lane & 1) * 32;
    const float* vp = v + (size_t)(base + tp * SS) * DIM + h * DH + dh0;
    int ut = tp >> 3;
    #pragma unroll
    for (int j4 = 0; j4 < 8; ++j4) {
      float4 f0 = *(const float4*)(vp + j4 * 4);
      #pragma unroll
      for (int c = 0; c < 4; ++c) {
        int d = dh0 + j4 * 4 + c;
        float val = (c == 0) ? f0.x : (c == 1) ? f0.y : (c == 2) ? f0.z : f0.w;
        VT[wave][d * 32 + ((ut ^ (d & 3)) << 3) + (tp & 7)] = f2bf(val);
      }
    }
  }

  // S = Q K^T  (32x32)
  f32x4 s[2][2];
  #pragma unroll
  for (int i = 0; i < 2; ++i)
    #pragma unroll
    for (int j = 0; j < 2; ++j) s[i][j] = (f32x4){0.f, 0.f, 0.f, 0.f};
  #pragma unroll
  for (int jt = 0; jt < 2; ++jt)
    #pragma unroll
    for (int i = 0; i < 2; ++i) {
      s[i][jt] = __builtin_amdgcn_mfma_f32_16x16x32_bf16(aq[i][0], bk[jt][0], s[i][jt], 0, 0, 0);
      s[i][jt] = __builtin_amdgcn_mfma_f32_16x16x32_bf16(aq[i][1], bk[jt][1], s[i][jt], 0, 0, 0);
    }

  // softclamp + exp + causal mask; bf16 P to wave-private LDS
  float rs[2][4];
  #pragma unroll
  for (int i = 0; i < 2; ++i)
    #pragma unroll
    for (int r = 0; r < 4; ++r) rs[i][r] = 0.f;
  #pragma unroll
  for (int i = 0; i < 2; ++i) {
    #pragma unroll
    for (int jt = 0; jt < 2; ++jt) {
      int pj = jt * 16 + c16;        // key t'
      int uj = pj >> 3;
      #pragma unroll
      for (int r = 0; r < 4; ++r) {
        int t = i * 16 + g * 4 + r;  // query t
        float p = softclamp_exp(s[i][jt][r] * 0.125f);
        unsigned short pb = (pj <= t) ? f2bf(p) : (unsigned short)0;
        rs[i][r] += bf2f(pb);
        Pw[wave][t * 32 + ((uj ^ (t & 3)) << 3) + (pj & 7)] = pb;
      }
    }
  }

  // O = P V
  short8 pa[2];
  #pragma unroll
  for (int i = 0; i < 2; ++i) {
    int prow = i * 16 + c16;
    pa[i] = *(const short8*)&Pw[wave][prow * 32 + ((g ^ (prow & 3)) << 3)];
  }
  f32x4 oacc[2][4];
  #pragma unroll
  for (int dt = 0; dt < 4; ++dt) {
    int d = dt * 16 + c16;
    short8 bv = *(const short8*)&VT[wave][d * 32 + ((g ^ (d & 3)) << 3)];
    #pragma unroll
    for (int i = 0; i < 2; ++i)
      oacc[i][dt] = __builtin_amdgcn_mfma_f32_16x16x32_bf16(
          pa[i], bv, (f32x4){0.f, 0.f, 0.f, 0.f}, 0, 0, 0);
  }

  // reduce row sums across the 16 lanes sharing g, then gate+write
  #pragma unroll
  for (int i = 0; i < 2; ++i)
    #pragma unroll
    for (int r = 0; r < 4; ++r) {
      float t = rs[i][r];
      t += __shfl_xor(t, 1); t += __shfl_xor(t, 2);
      t += __shfl_xor(t, 4); t += __shfl_xor(t, 8);
      rs[i][r] = t;
    }
  #pragma unroll
  for (int i = 0; i < 2; ++i) {
    #pragma unroll
    for (int r = 0; r < 4; ++r) {
      int t = i * 16 + g * 4 + r;
      int tok = base + t * SS;
      float gt = gate[(size_t)tok * HEADS + h] / rs[i][r];
      unsigned short* op = o + (size_t)tok * DIM + h * DH;
      #pragma unroll
      for (int dt = 0; dt < 4; ++dt)
        op[dt * 16 + c16] = f2bf(oacc[i][dt][r] * gt);
    }
  }
}

// ---------------- driver ----------------
extern "C" void kernel_launch(void* const* d_in, const int* in_sizes, int n_in,
                              void* d_out, int out_size, void* d_ws, size_t ws_size,
                              hipStream_t stream)
{
  const float* tokens = (const float*)d_in[0];
  const float* attn_norm_w = (const float*)d_in[1];
  const float* Wq   = (const float*)d_in[2];
  const float* Wk   = (const float*)d_in[3];
  const float* Wv   = (const float*)d_in[4];
  const float* Wo   = (const float*)d_in[5];
  const float* Wg   = (const float*)d_in[6];
  const float* Wmix = (const float*)d_in[7];
  const float* bmix = (const float*)d_in[8];
  const float* kgam = (const float*)d_in[9];
  const float* ffw  = (const float*)d_in[10];
  const float* Win  = (const float*)d_in[11];
  const float* bin  = (const float*)d_in[12];
  const float* Wout = (const float*)d_in[13];
  const float* bout = (const float*)d_in[14];
  const float* vrw  = (const float*)d_in[15];
  const float* vrW  = (const float*)d_in[16];
  const float* fnw  = (const float*)d_in[17];

  const size_t NT = (size_t)NTOK * DIM;   // 12,582,912
  float* ws  = (float*)d_ws;
  float* x   = ws;                        // NT f32
  float* q   = x  + NT;                   // NT f32
  float* k   = q  + NT;                   // NT f32
  float* v   = k  + NT;                   // NT f32
  float* rv  = v  + NT;                   // NT f32
  float* mix = rv + NT;                   // NTOK*12
  float* gate = mix + (size_t)NTOK * HEADS;
  unsigned short* tn   = (unsigned short*)(gate + (size_t)NTOK * HEADS); // NT bf16
  unsigned short* wqT  = tn + NT;                    // per-layer bf16 weights
  unsigned short* wkT  = wqT + 768 * 768;
  unsigned short* wvT  = wkT + 768 * 768;
  unsigned short* woT  = wvT + 768 * 768;
  unsigned short* winT = woT + 768 * 768;            // 4096*768
  unsigned short* woutT= winT + (size_t)4096 * 768;  // 768*2048
  unsigned short* vrWT = woutT + (size_t)768 * 2048; // 768*768
  unsigned short* hg   = (unsigned short*)q;         // 16384*2048 bf16, aliases q+k

  hipMemcpyAsync(x, tokens, NT * sizeof(float), hipMemcpyDeviceToDevice, stream);

  // value residual: rv = rmsnorm(tokens, vrw) @ vrW
  w_to_bt<<<dim3(24, 24), 256, 0, stream>>>(vrW, vrWT, DIM, DIM);
  rmsnorm_kernel<1><<<NTOK, 256, 0, stream>>>(tokens, vrw, tn);
  gemm_bf16<0><<<dim3(6, 128), 256, 0, stream>>>(
      tn, vrWT, rv, nullptr, nullptr, NTOK, DIM, DIM);

  for (int i = 0; i < DEPTH; ++i) {
    int is_time = ((i + 1) % 4 == 0) ? 1 : 0;
    // per-layer weight conversion (bf16, transposed)
    w_to_bt<<<dim3(24, 24), 256, 0, stream>>>(Wq + (size_t)i * DIM * DIM, wqT, DIM, DIM);
    w_to_bt<<<dim3(24, 24), 256, 0, stream>>>(Wk + (size_t)i * DIM * DIM, wkT, DIM, DIM);
    w_to_bt<<<dim3(24, 24), 256, 0, stream>>>(Wv + (size_t)i * DIM * DIM, wvT, DIM, DIM);
    w_to_bt<<<dim3(24, 24), 256, 0, stream>>>(Wo + (size_t)i * DIM * DIM, woT, DIM, DIM);
    w_to_bt<<<dim3(128, 24), 256, 0, stream>>>(Win + (size_t)i * DIM * 2 * DFF, winT, DIM, 2 * DFF);
    w_to_bt<<<dim3(24, 64), 256, 0, stream>>>(Wout + (size_t)i * DFF * DIM, woutT, DFF, DIM);

    rmsnorm_kernel<1><<<NTOK, 256, 0, stream>>>(x, attn_norm_w + (size_t)i * DIM, tn);
    gemm_bf16<0><<<dim3(6, 128), 256, 0, stream>>>(tn, wqT, q, nullptr, nullptr, NTOK, DIM, DIM);
    gemm_bf16<0><<<dim3(6, 128), 256, 0, stream>>>(tn, wkT, k, nullptr, nullptr, NTOK, DIM, DIM);
    gemm_bf16<0><<<dim3(6, 128), 256, 0, stream>>>(tn, wvT, v, nullptr, nullptr, NTOK, DIM, DIM);
    proj12_kernel<<<NTOK / 4, 256, 0, stream>>>(
        tn, Wmix + (size_t)i * DIM * HEADS, bmix + (size_t)i * HEADS, mix);
    proj12_kernel<<<NTOK / 4, 256, 0, stream>>>(
        tn, Wg + (size_t)i * DIM * HEADS, nullptr, gate);
    qkv_fix_kernel<<<dim3(NTOK), 768, 0, stream>>>(
        q, k, v, rv, mix, kgam + (size_t)i * HEADS * DH, is_time);
    if (is_time)
      attn_time_mfma<<<dim3((BB * SS) / 4, HEADS), 256, 0, stream>>>(
          q, k, v, gate, tn);
    else
      attn_mfma_kernel<<<dim3(BB * TT * 2, HEADS), 256, 0, stream>>>(
          q, k, v, gate, tn);
    gemm_bf16<1><<<dim3(6, 128), 256, 0, stream>>>(tn, woT, x, nullptr, nullptr, NTOK, DIM, DIM);
    // FF
    rmsnorm_kernel<1><<<NTOK, 256, 0, stream>>>(x, ffw + (size_t)i * DIM, tn);
    gemm_bf16<2><<<dim3(16, 128), 256, 0, stream>>>(
        tn, winT, nullptr, hg, bin + (size_t)i * 2 * DFF, NTOK, DFF, DIM);
    gemm_bf16<3><<<dim3(16, 128), 256, 0, stream>>>(
        tn, winT + (size_t)DFF * DIM, nullptr, hg, bin + (size_t)i * 2 * DFF + DFF,
        NTOK, DFF, DIM);
    gemm_bf16<1><<<dim3(6, 128), 256, 0, stream>>>(
        hg, woutT, x, nullptr, bout + (size_t)i * DIM, NTOK, DIM, DFF);
  }
  rmsnorm_kernel<0><<<NTOK, 256, 0, stream>>>(x, fnw, (float*)d_out);
}

// Round 3
// 5029.794 us; speedup vs baseline: 1.4684x; 1.2455x over previous
//
#include <hip/hip_runtime.h>
#include <cmath>

#define DIM 768
#define DEPTH 8
#define HEADS 12
#define DH 64
#define DFF 2048
#define NTOK 16384   // B*T*S = 2*32*256
#define BB 2
#define TT 32
#define SS 256
#define LDQ 2304     // packed qkv row stride (3*768)

typedef __attribute__((ext_vector_type(8))) short short8;
typedef __attribute__((ext_vector_type(4))) float f32x4;

__device__ __forceinline__ float sigmoidf_(float x) { return 1.0f / (1.0f + __expf(-x)); }
__device__ __forceinline__ float geluf_(float x) {
  return 0.5f * x * (1.0f + erff(x * 0.70710678118654752f));
}
__device__ __forceinline__ unsigned short f2bf(float x) {
  union { float f; unsigned int u; } a; a.f = x;
  unsigned int r = a.u + 0x7fff + ((a.u >> 16) & 1);   // RNE
  return (unsigned short)(r >> 16);
}
__device__ __forceinline__ float bf2f(unsigned short h) {
  union { unsigned int u; float f; } a; a.u = ((unsigned int)h) << 16;
  return a.f;
}
__device__ __forceinline__ void load_lds16(const void* g, void* l) {
  __builtin_amdgcn_global_load_lds(
      (const __attribute__((address_space(1))) unsigned int*)g,
      (__attribute__((address_space(3))) unsigned int*)l, 16, 0, 0);
}
// softclamp+exp: p = exp(50*tanh(sv/50)) = 2^72.1347 * 2^(-144.2695/(e^{sv/25}+1))
__device__ __forceinline__ float softclamp_exp(float sv) {
  float a = exp2f(sv * 0.057707802f);
  float rc = __builtin_amdgcn_rcpf(a + 1.0f);
  return exp2f(fmaf(-144.26950408f, rc, 72.13475204f));
}

// ---------------- RMSNorm: one block per row of 768 ----------------
template<int BF>
__global__ __launch_bounds__(256) void rmsnorm_kernel(
    const float* __restrict__ x, const float* __restrict__ w, void* __restrict__ outp)
{
  int row = blockIdx.x;
  int tid = threadIdx.x;
  const float* xr = x + (size_t)row * DIM;
  float v0 = xr[tid], v1 = xr[tid + 256], v2 = xr[tid + 512];
  float ss = v0 * v0 + v1 * v1 + v2 * v2;
  #pragma unroll
  for (int off = 32; off; off >>= 1) ss += __shfl_xor(ss, off);
  __shared__ float sred[4];
  if ((tid & 63) == 0) sred[tid >> 6] = ss;
  __syncthreads();
  float tot = sred[0] + sred[1] + sred[2] + sred[3];
  float r = rsqrtf(tot * (1.0f / DIM) + 1e-6f);
  if (BF) {
    unsigned short* orow = (unsigned short*)outp + (size_t)row * DIM;
    orow[tid]       = f2bf(v0 * r * w[tid]);
    orow[tid + 256] = f2bf(v1 * r * w[tid + 256]);
    orow[tid + 512] = f2bf(v2 * r * w[tid + 512]);
  } else {
    float* orow = (float*)outp + (size_t)row * DIM;
    orow[tid]       = v0 * r * w[tid];
    orow[tid + 256] = v1 * r * w[tid + 256];
    orow[tid + 512] = v2 * r * w[tid + 512];
  }
}

// ---------------- weight convert+transpose: W[K][N] f32 -> WT[N][K] bf16 ----------------
__global__ __launch_bounds__(256) void w_to_bt(
    const float* __restrict__ W, unsigned short* __restrict__ WT, int K, int N)
{
  __shared__ float t[32][33];
  int n0 = blockIdx.x * 32, k0 = blockIdx.y * 32;
  int c = threadIdx.x & 31, r8 = threadIdx.x >> 5;
  #pragma unroll
  for (int rr = r8; rr < 32; rr += 8)
    t[rr][c] = W[(size_t)(k0 + rr) * N + n0 + c];
  __syncthreads();
  #pragma unroll
  for (int rn = r8; rn < 32; rn += 8)
    WT[(size_t)(n0 + rn) * K + k0 + c] = f2bf(t[c][rn]);
}

// ---------------- bf16 MFMA GEMM: 128x128 tile, BK=32 (m97 structure) ----------------
// A: MxK bf16 row-major. BT: NxK bf16 row-major (= B transposed).
// MODE 0: Cf = A@B (+bias)            (fp32 out)
// MODE 1: Cf += A@B (+bias)           (fp32 accumulate)
// MODE 2: Hg = bf16(A@B + bias)       (bf16 out)
template<int MODE>
__global__ __launch_bounds__(256) void gemm_bf16(
    const unsigned short* __restrict__ A, const unsigned short* __restrict__ BT,
    float* __restrict__ Cf, unsigned short* __restrict__ Hg,
    const float* __restrict__ bias, int M, int N, int K)
{
  __shared__ unsigned short As[128 * 32];
  __shared__ unsigned short Bs[128 * 32];
  const int tid = threadIdx.x;
  const int wave = tid >> 6;
  const int lane = tid & 63;
  const int bm = blockIdx.y * 128;
  const int bn = blockIdx.x * 128;
  const int wm = (wave & 1) * 64;
  const int wn = (wave >> 1) * 64;

  f32x4 acc[4][4];
  #pragma unroll
  for (int i = 0; i < 4; ++i)
    #pragma unroll
    for (int j = 0; j < 4; ++j) acc[i][j] = (f32x4){0.f, 0.f, 0.f, 0.f};

  const int srow = wave * 32 + (lane >> 2);
  const int skoff = (lane & 3) * 8;            // ushorts (16 B)
  const unsigned short* gA = A + (size_t)(bm + srow) * K + skoff;
  const unsigned short* gB = BT + (size_t)(bn + srow) * K + skoff;
  unsigned short* lA = &As[(wave * 32) * 32];
  unsigned short* lB = &Bs[(wave * 32) * 32];

  const int fr = lane & 15;
  const int fq = (lane >> 4) * 8;

  for (int k0 = 0; k0 < K; k0 += 32) {
    load_lds16(gA + k0, lA);
    load_lds16(gA + k0 + 16 * K, lA + 16 * 32);
    load_lds16(gB + k0, lB);
    load_lds16(gB + k0 + 16 * K, lB + 16 * 32);
    __syncthreads();
    short8 a[4], b[4];
    #pragma unroll
    for (int i = 0; i < 4; ++i)
      a[i] = *(const short8*)&As[(wm + 16 * i + fr) * 32 + fq];
    #pragma unroll
    for (int j = 0; j < 4; ++j)
      b[j] = *(const short8*)&Bs[(wn + 16 * j + fr) * 32 + fq];
    #pragma unroll
    for (int i = 0; i < 4; ++i)
      #pragma unroll
      for (int j = 0; j < 4; ++j)
        acc[i][j] = __builtin_amdgcn_mfma_f32_16x16x32_bf16(a[i], b[j], acc[i][j], 0, 0, 0);
    __syncthreads();
  }

  const int crow0 = bm + wm + (lane >> 4) * 4;
  const int ccol0 = bn + wn + fr;
  float bv[4];
  #pragma unroll
  for (int j = 0; j < 4; ++j) bv[j] = bias ? bias[ccol0 + 16 * j] : 0.0f;
  #pragma unroll
  for (int i = 0; i < 4; ++i) {
    #pragma unroll
    for (int r = 0; r < 4; ++r) {
      int row = crow0 + 16 * i + r;
      #pragma unroll
      for (int j = 0; j < 4; ++j) {
        int col = ccol0 + 16 * j;
        size_t idx = (size_t)row * N + col;
        float val = acc[i][j][r] + bv[j];
        if (MODE == 0) Cf[idx] = val;
        else if (MODE == 1) Cf[idx] += val;
        else Hg[idx] = f2bf(val);
      }
    }
  }
}

// ---------------- fused FF in-proj: Hg = bf16((A@Ba + ba) * gelu(A@Bg + bg)) ----------------
__global__ __launch_bounds__(256, 2) void gemm_ff(
    const unsigned short* __restrict__ A, const unsigned short* __restrict__ BTa,
    const unsigned short* __restrict__ BTg, unsigned short* __restrict__ Hg,
    const float* __restrict__ ba, const float* __restrict__ bg, int M, int N, int K)
{
  __shared__ unsigned short As[128 * 32];
  __shared__ unsigned short Bas[128 * 32];
  __shared__ unsigned short Bgs[128 * 32];
  const int tid = threadIdx.x;
  const int wave = tid >> 6;
  const int lane = tid & 63;
  const int bm = blockIdx.y * 128;
  const int bn = blockIdx.x * 128;
  const int wm = (wave & 1) * 64;
  const int wn = (wave >> 1) * 64;

  f32x4 acca[4][4], accg[4][4];
  #pragma unroll
  for (int i = 0; i < 4; ++i)
    #pragma unroll
    for (int j = 0; j < 4; ++j) {
      acca[i][j] = (f32x4){0.f, 0.f, 0.f, 0.f};
      accg[i][j] = (f32x4){0.f, 0.f, 0.f, 0.f};
    }

  const int srow = wave * 32 + (lane >> 2);
  const int skoff = (lane & 3) * 8;
  const unsigned short* gA  = A   + (size_t)(bm + srow) * K + skoff;
  const unsigned short* gBa = BTa + (size_t)(bn + srow) * K + skoff;
  const unsigned short* gBg = BTg + (size_t)(bn + srow) * K + skoff;
  unsigned short* lA  = &As[(wave * 32) * 32];
  unsigned short* lBa = &Bas[(wave * 32) * 32];
  unsigned short* lBg = &Bgs[(wave * 32) * 32];

  const int fr = lane & 15;
  const int fq = (lane >> 4) * 8;

  for (int k0 = 0; k0 < K; k0 += 32) {
    load_lds16(gA + k0, lA);
    load_lds16(gA + k0 + 16 * K, lA + 16 * 32);
    load_lds16(gBa + k0, lBa);
    load_lds16(gBa + k0 + 16 * K, lBa + 16 * 32);
    load_lds16(gBg + k0, lBg);
    load_lds16(gBg + k0 + 16 * K, lBg + 16 * 32);
    __syncthreads();
    short8 a[4], b1[4], b2[4];
    #pragma unroll
    for (int i = 0; i < 4; ++i)
      a[i] = *(const short8*)&As[(wm + 16 * i + fr) * 32 + fq];
    #pragma unroll
    for (int j = 0; j < 4; ++j) {
      b1[j] = *(const short8*)&Bas[(wn + 16 * j + fr) * 32 + fq];
      b2[j] = *(const short8*)&Bgs[(wn + 16 * j + fr) * 32 + fq];
    }
    #pragma unroll
    for (int i = 0; i < 4; ++i)
      #pragma unroll
      for (int j = 0; j < 4; ++j) {
        acca[i][j] = __builtin_amdgcn_mfma_f32_16x16x32_bf16(a[i], b1[j], acca[i][j], 0, 0, 0);
        accg[i][j] = __builtin_amdgcn_mfma_f32_16x16x32_bf16(a[i], b2[j], accg[i][j], 0, 0, 0);
      }
    __syncthreads();
  }

  const int crow0 = bm + wm + (lane >> 4) * 4;
  const int ccol0 = bn + wn + fr;
  float bva[4], bvg[4];
  #pragma unroll
  for (int j = 0; j < 4; ++j) {
    bva[j] = ba[ccol0 + 16 * j];
    bvg[j] = bg[ccol0 + 16 * j];
  }
  #pragma unroll
  for (int i = 0; i < 4; ++i) {
    #pragma unroll
    for (int r = 0; r < 4; ++r) {
      int row = crow0 + 16 * i + r;
      #pragma unroll
      for (int j = 0; j < 4; ++j) {
        int col = ccol0 + 16 * j;
        float av = acca[i][j][r] + bva[j];
        float gv = accg[i][j][r] + bvg[j];
        Hg[(size_t)row * N + col] = f2bf(av * geluf_(gv));
      }
    }
  }
}

// ---------------- N=12 dual projection + sigmoid (mix & gate in one pass) ----------------
__global__ __launch_bounds__(256) void proj12x2_kernel(
    const unsigned short* __restrict__ A, const float* __restrict__ Bw1,
    const float* __restrict__ b1, const float* __restrict__ Bw2,
    float* __restrict__ out1, float* __restrict__ out2)
{
  int row = blockIdx.x * 4 + (threadIdx.x >> 6);
  int lane = threadIdx.x & 63;
  const unsigned short* ar = A + (size_t)row * DIM;
  float acc1[HEADS], acc2[HEADS];
  #pragma unroll
  for (int j = 0; j < HEADS; ++j) { acc1[j] = 0.0f; acc2[j] = 0.0f; }
  for (int k2 = lane; k2 < DIM; k2 += 64) {
    float a = bf2f(ar[k2]);
    const float* bw1 = Bw1 + (size_t)k2 * HEADS;
    const float* bw2 = Bw2 + (size_t)k2 * HEADS;
    #pragma unroll
    for (int j = 0; j < HEADS; ++j) {
      acc1[j] = fmaf(a, bw1[j], acc1[j]);
      acc2[j] = fmaf(a, bw2[j], acc2[j]);
    }
  }
  #pragma unroll
  for (int j = 0; j < HEADS; ++j) {
    #pragma unroll
    for (int off = 32; off; off >>= 1) {
      acc1[j] += __shfl_xor(acc1[j], off);
      acc2[j] += __shfl_xor(acc2[j], off);
    }
  }
  if (lane < HEADS) {
    out1[(size_t)row * HEADS + lane] = sigmoidf_(acc1[lane] + b1[lane]);
    out2[(size_t)row * HEADS + lane] = sigmoidf_(acc2[lane]);
  }
}

// ---------------- qkv postprocess (bf16): v-lerp, k-norm+gamma, rotary ----------------
__global__ __launch_bounds__(768) void qkv_fix_kernel(
    unsigned short* __restrict__ qkv, const unsigned short* __restrict__ rvb,
    const float* __restrict__ mix, const float* __restrict__ kgam, int is_time)
{
  int tok = blockIdx.x;
  int h = threadIdx.x >> 6;
  int d = threadIdx.x & 63;
  size_t rowb = (size_t)tok * LDQ + h * DH + d;
  float kv = bf2f(qkv[rowb + 768]);
  float ss = kv * kv;
  #pragma unroll
  for (int off = 32; off; off >>= 1) ss += __shfl_xor(ss, off);
  float nrm = fmaxf(sqrtf(ss), 1e-12f);
  kv = kv / nrm * (kgam[h * DH + d] + 1.0f) * 8.0f;   // sqrt(DH)=8
  float mv = mix[(size_t)tok * HEADS + h];
  float vv = bf2f(qkv[rowb + 1536]);
  float rvv = bf2f(rvb[(size_t)tok * DIM + h * DH + d]);
  qkv[rowb + 1536] = f2bf(vv + mv * (rvv - vv));
  float qv = bf2f(qkv[rowb]);
  if (is_time) {
    int t = (tok >> 8) & 31;          // token = (b*32+t)*256+s
    int j = d & 31;
    float ang = (float)t * __expf(-(float)j * (9.210340371976184f / 32.0f));
    float cs = cosf(ang), sn = sinf(ang);
    float qp = __shfl_xor(qv, 32);
    float kp = __shfl_xor(kv, 32);
    float sgn = (d < 32) ? -1.0f : 1.0f;
    qv = qv * cs + sgn * qp * sn;
    kv = kv * cs + sgn * kp * sn;
  }
  qkv[rowb] = f2bf(qv);
  qkv[rowb + 768] = f2bf(kv);
}

// ---------------- MFMA space attention (bf16 in) ----------------
// grid (BB*TT*2, HEADS): block = 128 q-rows of one (seq bp, head h); wave = 32 q-rows.
// Fragment layouts (16x16x32 bf16): A: lane holds A[row=lane&15][k=(lane>>4)*8+i]
//   B: lane holds B[k=(lane>>4)*8+i][col=lane&15]; C: C[row=(lane>>4)*4+r][col=lane&15]
__global__ __launch_bounds__(256, 3) void attn_mfma_kernel(
    const unsigned short* __restrict__ q, const unsigned short* __restrict__ k,
    const unsigned short* __restrict__ v, const float* __restrict__ gate,
    unsigned short* __restrict__ o)
{
  __shared__ __align__(16) unsigned short Ks[128 * 64];    // 16 KB, u^=row&7
  __shared__ __align__(16) unsigned short VsT[64 * 128];   // 16 KB, u^=d&15
  __shared__ __align__(16) unsigned short Pw[4][32 * 64];  // 16 KB, u^=row&7
  const int tid = threadIdx.x;
  const int wave = tid >> 6;
  const int lane = tid & 63;
  const int g = lane >> 4;
  const int c16 = lane & 15;
  const int bp = blockIdx.x >> 1;
  const int qh = blockIdx.x & 1;
  const int h = blockIdx.y;
  const size_t qoff = (size_t)bp * SS * LDQ + h * DH;
  const int qbase = qh * 128 + wave * 32;

  // Q fragments: wave owns rows [qbase, qbase+32)
  short8 aq[2][2];
  #pragma unroll
  for (int i = 0; i < 2; ++i) {
    const unsigned short* qp = q + qoff + (size_t)(qbase + i * 16 + c16) * LDQ;
    #pragma unroll
    for (int cc = 0; cc < 2; ++cc)
      aq[i][cc] = *(const short8*)(qp + cc * 32 + g * 8);
  }

  f32x4 oacc[2][4];
  float rs[2][4];
  #pragma unroll
  for (int i = 0; i < 2; ++i)
    #pragma unroll
    for (int j = 0; j < 4; ++j) {
      oacc[i][j] = (f32x4){0.f, 0.f, 0.f, 0.f};
      rs[i][j] = 0.f;
    }

  // K staging via global_load_lds: LDS linear dest, pre-swizzled global source.
  // slot f = (row, u'): src unit index = u' ^ (row&7)
  const int srow_ = tid >> 3;          // slot row base (per-iter +32)
  const int su_ = tid & 7;

  for (int half = 0; half < 2; ++half) {
    const int r0 = half * 128;
    #pragma unroll
    for (int it = 0; it < 4; ++it) {
      int row = srow_ + it * 32;
      const unsigned short* src =
          k + qoff + (size_t)(r0 + row) * LDQ + ((su_ ^ (row & 7)) << 3);
      load_lds16(src, &Ks[(wave * 64 + it * 2048 / 8) * 8]);  // dest base: this wave's 1KB chunk
    }
    // stage V transposed: VsT[d][j]
    #pragma unroll
    for (int it = 0; it < 4; ++it) {
      int f = tid + it * 256;
      int j = f & 127, dq = f >> 7;
      short8 t = *(const short8*)(v + qoff + (size_t)(r0 + j) * LDQ + dq * 8);
      int u = j >> 3;
      #pragma unroll
      for (int c = 0; c < 8; ++c) {
        int d = dq * 8 + c;
        VsT[d * 128 + ((u ^ (d & 15)) << 3) + (j & 7)] = (unsigned short)t[c];
      }
    }
    __syncthreads();

    #pragma unroll
    for (int jc = 0; jc < 2; ++jc) {
      const int lr0 = jc * 64;
      // ---- S = Q K^T for 32 q-rows x 64 k-cols ----
      f32x4 s[2][4];
      #pragma unroll
      for (int i = 0; i < 2; ++i)
        #pragma unroll
        for (int j = 0; j < 4; ++j) s[i][j] = (f32x4){0.f, 0.f, 0.f, 0.f};
      #pragma unroll
      for (int jt = 0; jt < 4; ++jt) {
        int row = lr0 + jt * 16 + c16;
        short8 b0 = *(const short8*)&Ks[row * 64 + ((g ^ (row & 7)) << 3)];
        short8 b1 = *(const short8*)&Ks[row * 64 + (((4 + g) ^ (row & 7)) << 3)];
        #pragma unroll
        for (int i = 0; i < 2; ++i) {
          s[i][jt] = __builtin_amdgcn_mfma_f32_16x16x32_bf16(aq[i][0], b0, s[i][jt], 0, 0, 0);
          s[i][jt] = __builtin_amdgcn_mfma_f32_16x16x32_bf16(aq[i][1], b1, s[i][jt], 0, 0, 0);
        }
      }
      // ---- softclamp + exp; bf16 P to wave-private LDS ----
      #pragma unroll
      for (int i = 0; i < 2; ++i) {
        #pragma unroll
        for (int jt = 0; jt < 4; ++jt) {
          int pj = jt * 16 + c16;
          int uj = pj >> 3;
          #pragma unroll
          for (int r = 0; r < 4; ++r) {
            float p = softclamp_exp(s[i][jt][r] * 0.125f);
            unsigned short pb = f2bf(p);
            rs[i][r] += bf2f(pb);
            int prow = i * 16 + g * 4 + r;
            Pw[wave][prow * 64 + ((uj ^ (prow & 7)) << 3) + (pj & 7)] = pb;
          }
        }
      }
      // ---- O += P V ----
      #pragma unroll
      for (int jj = 0; jj < 2; ++jj) {
        short8 pa[2];
        #pragma unroll
        for (int i = 0; i < 2; ++i) {
          int prow = i * 16 + c16;
          int u = jj * 4 + g;
          pa[i] = *(const short8*)&Pw[wave][prow * 64 + ((u ^ (prow & 7)) << 3)];
        }
        const int jl = lr0 + jj * 32 + g * 8;
        const int uv = jl >> 3;
        #pragma unroll
        for (int dt = 0; dt < 4; ++dt) {
          int d = dt * 16 + c16;
          short8 bv = *(const short8*)&VsT[d * 128 + ((uv ^ (d & 15)) << 3)];
          #pragma unroll
          for (int i = 0; i < 2; ++i)
            oacc[i][dt] = __builtin_amdgcn_mfma_f32_16x16x32_bf16(pa[i], bv, oacc[i][dt], 0, 0, 0);
        }
      }
    }
    __syncthreads();
  }

  #pragma unroll
  for (int i = 0; i < 2; ++i)
    #pragma unroll
    for (int r = 0; r < 4; ++r) {
      float t = rs[i][r];
      t += __shfl_xor(t, 1); t += __shfl_xor(t, 2);
      t += __shfl_xor(t, 4); t += __shfl_xor(t, 8);
      rs[i][r] = t;
    }
  #pragma unroll
  for (int i = 0; i < 2; ++i) {
    #pragma unroll
    for (int r = 0; r < 4; ++r) {
      int row = qbase + i * 16 + g * 4 + r;
      int tq = bp * SS + row;
      float gt = gate[(size_t)tq * HEADS + h] / rs[i][r];
      unsigned short* op = o + (size_t)tq * DIM + h * DH;
      #pragma unroll
      for (int dt = 0; dt < 4; ++dt)
        op[dt * 16 + c16] = f2bf(oacc[i][dt][r] * gt);
    }
  }
}

// ---------------- MFMA time attention (bf16 in): wave = one (b,s) sequence ----------------
__global__ __launch_bounds__(256, 3) void attn_time_mfma(
    const unsigned short* __restrict__ q, const unsigned short* __restrict__ k,
    const unsigned short* __restrict__ v, const float* __restrict__ gate,
    unsigned short* __restrict__ o)
{
  __shared__ __align__(16) unsigned short VT[4][64 * 32];  // [d][t'], u^=d&3
  __shared__ __align__(16) unsigned short Pw[4][32 * 32];  // [t][t'], u^=t&3
  const int tid = threadIdx.x;
  const int wave = tid >> 6;
  const int lane = tid & 63;
  const int g = lane >> 4;
  const int c16 = lane & 15;
  const int h = blockIdx.y;
  const int sp = blockIdx.x * 4 + wave;                 // 0..511
  const int base = (sp >> 8) * (TT * SS) + (sp & 255);  // b*8192 + s

  short8 aq[2][2], bk[2][2];
  #pragma unroll
  for (int i = 0; i < 2; ++i) {
    const unsigned short* qp = q + (size_t)(base + (i * 16 + c16) * SS) * LDQ + h * DH;
    const unsigned short* kp = k + (size_t)(base + (i * 16 + c16) * SS) * LDQ + h * DH;
    #pragma unroll
    for (int cc = 0; cc < 2; ++cc) {
      aq[i][cc] = *(const short8*)(qp + cc * 32 + g * 8);
      bk[i][cc] = *(const short8*)(kp + cc * 32 + g * 8);
    }
  }

  // stage V transposed: lane handles t' = lane>>1, d-half = (lane&1)*32
  {
    int tp = lane >> 1;
    int dh0 = (lane & 1) * 32;
    const unsigned short* vp = v + (size_t)(base + tp * SS) * LDQ + h * DH + dh0;
    int ut = tp >> 3;
    #pragma unroll
    for (int j4 = 0; j4 < 4; ++j4) {
      short8 t = *(const short8*)(vp + j4 * 8);
      #pragma unroll
      for (int c = 0; c < 8; ++c) {
        int d = dh0 + j4 * 8 + c;
        VT[wave][d * 32 + ((ut ^ (d & 3)) << 3) + (tp & 7)] = (unsigned short)t[c];
      }
    }
  }

  // S = Q K^T (32x32)
  f32x4 s[2][2];
  #pragma unroll
  for (int i = 0; i < 2; ++i)
    #pragma unroll
    for (int j = 0; j < 2; ++j) s[i][j] = (f32x4){0.f, 0.f, 0.f, 0.f};
  #pragma unroll
  for (int jt = 0; jt < 2; ++jt)
    #pragma unroll
    for (int i = 0; i < 2; ++i) {
      s[i][jt] = __builtin_amdgcn_mfma_f32_16x16x32_bf16(aq[i][0], bk[jt][0], s[i][jt], 0, 0, 0);
      s[i][jt] = __builtin_amdgcn_mfma_f32_16x16x32_bf16(aq[i][1], bk[jt][1], s[i][jt], 0, 0, 0);
    }

  // softclamp + exp + causal mask; bf16 P to wave-private LDS
  float rs[2][4];
  #pragma unroll
  for (int i = 0; i < 2; ++i)
    #pragma unroll
    for (int r = 0; r < 4; ++r) rs[i][r] = 0.f;
  #pragma unroll
  for (int i = 0; i < 2; ++i) {
    #pragma unroll
    for (int jt = 0; jt < 2; ++jt) {
      int pj = jt * 16 + c16;
      int uj = pj >> 3;
      #pragma unroll
      for (int r = 0; r < 4; ++r) {
        int t = i * 16 + g * 4 + r;
        float p = softclamp_exp(s[i][jt][r] * 0.125f);
        unsigned short pb = (pj <= t) ? f2bf(p) : (unsigned short)0;
        rs[i][r] += bf2f(pb);
        Pw[wave][t * 32 + ((uj ^ (t & 3)) << 3) + (pj & 7)] = pb;
      }
    }
  }

  // O = P V
  short8 pa[2];
  #pragma unroll
  for (int i = 0; i < 2; ++i) {
    int prow = i * 16 + c16;
    pa[i] = *(const short8*)&Pw[wave][prow * 32 + ((g ^ (prow & 3)) << 3)];
  }
  f32x4 oacc[2][4];
  #pragma unroll
  for (int dt = 0; dt < 4; ++dt) {
    int d = dt * 16 + c16;
    short8 bv = *(const short8*)&VT[wave][d * 32 + ((g ^ (d & 3)) << 3)];
    #pragma unroll
    for (int i = 0; i < 2; ++i)
      oacc[i][dt] = __builtin_amdgcn_mfma_f32_16x16x32_bf16(
          pa[i], bv, (f32x4){0.f, 0.f, 0.f, 0.f}, 0, 0, 0);
  }

  #pragma unroll
  for (int i = 0; i < 2; ++i)
    #pragma unroll
    for (int r = 0; r < 4; ++r) {
      float t = rs[i][r];
      t += __shfl_xor(t, 1); t += __shfl_xor(t, 2);
      t += __shfl_xor(t, 4); t += __shfl_xor(t, 8);
      rs[i][r] = t;
    }
  #pragma unroll
  for (int i = 0; i < 2; ++i) {
    #pragma unroll
    for (int r = 0; r < 4; ++r) {
      int t = i * 16 + g * 4 + r;
      int tok = base + t * SS;
      float gt = gate[(size_t)tok * HEADS + h] / rs[i][r];
      unsigned short* op = o + (size_t)tok * DIM + h * DH;
      #pragma unroll
      for (int dt = 0; dt < 4; ++dt)
        op[dt * 16 + c16] = f2bf(oacc[i][dt][r] * gt);
    }
  }
}

// ---------------- driver ----------------
extern "C" void kernel_launch(void* const* d_in, const int* in_sizes, int n_in,
                              void* d_out, int out_size, void* d_ws, size_t ws_size,
                              hipStream_t stream)
{
  const float* tokens = (const float*)d_in[0];
  const float* attn_norm_w = (const float*)d_in[1];
  const float* Wq   = (const float*)d_in[2];
  const float* Wk   = (const float*)d_in[3];
  const float* Wv   = (const float*)d_in[4];
  const float* Wo   = (const float*)d_in[5];
  const float* Wg   = (const float*)d_in[6];
  const float* Wmix = (const float*)d_in[7];
  const float* bmix = (const float*)d_in[8];
  const float* kgam = (const float*)d_in[9];
  const float* ffw  = (const float*)d_in[10];
  const float* Win  = (const float*)d_in[11];
  const float* bin  = (const float*)d_in[12];
  const float* Wout = (const float*)d_in[13];
  const float* bout = (const float*)d_in[14];
  const float* vrw  = (const float*)d_in[15];
  const float* vrW  = (const float*)d_in[16];
  const float* fnw  = (const float*)d_in[17];

  const size_t NT = (size_t)NTOK * DIM;   // 12,582,912
  float* ws  = (float*)d_ws;
  float* x   = ws;                        // NT f32
  float* mix = x + NT;                    // NTOK*12
  float* gate = mix + (size_t)NTOK * HEADS;
  unsigned short* tn   = (unsigned short*)(gate + (size_t)NTOK * HEADS); // NT bf16
  unsigned short* qkv  = tn + NT;                        // NTOK*2304 bf16
  unsigned short* rvb  = qkv + (size_t)NTOK * LDQ;       // NT bf16
  unsigned short* wqkvT = rvb + NT;                      // 2304*768
  unsigned short* woT  = wqkvT + (size_t)2304 * 768;     // 768*768
  unsigned short* winT = woT + (size_t)768 * 768;        // 4096*768
  unsigned short* woutT= winT + (size_t)4096 * 768;      // 768*2048
  unsigned short* vrWT = woutT + (size_t)768 * 2048;     // 768*768
  unsigned short* hg   = qkv;   // FF hidden aliases qkv (33.5M <= 37.7M elems)

  hipMemcpyAsync(x, tokens, NT * sizeof(float), hipMemcpyDeviceToDevice, stream);

  // value residual: rvb = bf16(rmsnorm(tokens, vrw) @ vrW)
  w_to_bt<<<dim3(24, 24), 256, 0, stream>>>(vrW, vrWT, DIM, DIM);
  rmsnorm_kernel<1><<<NTOK, 256, 0, stream>>>(tokens, vrw, tn);
  gemm_bf16<2><<<dim3(6, 128), 256, 0, stream>>>(
      tn, vrWT, nullptr, rvb, nullptr, NTOK, DIM, DIM);

  for (int i = 0; i < DEPTH; ++i) {
    int is_time = ((i + 1) % 4 == 0) ? 1 : 0;
    // per-layer weight conversion (bf16, transposed); q/k/v packed into one 2304xK
    w_to_bt<<<dim3(24, 24), 256, 0, stream>>>(Wq + (size_t)i * DIM * DIM, wqkvT, DIM, DIM);
    w_to_bt<<<dim3(24, 24), 256, 0, stream>>>(Wk + (size_t)i * DIM * DIM, wqkvT + (size_t)768 * 768, DIM, DIM);
    w_to_bt<<<dim3(24, 24), 256, 0, stream>>>(Wv + (size_t)i * DIM * DIM, wqkvT + (size_t)1536 * 768, DIM, DIM);
    w_to_bt<<<dim3(24, 24), 256, 0, stream>>>(Wo + (size_t)i * DIM * DIM, woT, DIM, DIM);
    w_to_bt<<<dim3(128, 24), 256, 0, stream>>>(Win + (size_t)i * DIM * 2 * DFF, winT, DIM, 2 * DFF);
    w_to_bt<<<dim3(24, 64), 256, 0, stream>>>(Wout + (size_t)i * DFF * DIM, woutT, DFF, DIM);

    rmsnorm_kernel<1><<<NTOK, 256, 0, stream>>>(x, attn_norm_w + (size_t)i * DIM, tn);
    // fused qkv projection -> packed bf16 [tok][2304]
    gemm_bf16<2><<<dim3(18, 128), 256, 0, stream>>>(
        tn, wqkvT, nullptr, qkv, nullptr, NTOK, LDQ, DIM);
    proj12x2_kernel<<<NTOK / 4, 256, 0, stream>>>(
        tn, Wmix + (size_t)i * DIM * HEADS, bmix + (size_t)i * HEADS,
        Wg + (size_t)i * DIM * HEADS, mix, gate);
    qkv_fix_kernel<<<dim3(NTOK), 768, 0, stream>>>(
        qkv, rvb, mix, kgam + (size_t)i * HEADS * DH, is_time);
    if (is_time)
      attn_time_mfma<<<dim3((BB * SS) / 4, HEADS), 256, 0, stream>>>(
          qkv, qkv + 768, qkv + 1536, gate, tn);
    else
      attn_mfma_kernel<<<dim3(BB * TT * 2, HEADS), 256, 0, stream>>>(
          qkv, qkv + 768, qkv + 1536, gate, tn);
    gemm_bf16<1><<<dim3(6, 128), 256, 0, stream>>>(tn, woT, x, nullptr, nullptr, NTOK, DIM, DIM);
    // FF (fused in-proj + gelu-mul)
    rmsnorm_kernel<1><<<NTOK, 256, 0, stream>>>(x, ffw + (size_t)i * DIM, tn);
    gemm_ff<<<dim3(16, 128), 256, 0, stream>>>(
        tn, winT, winT + (size_t)DFF * DIM, hg,
        bin + (size_t)i * 2 * DFF, bin + (size_t)i * 2 * DFF + DFF, NTOK, DFF, DIM);
    gemm_bf16<1><<<dim3(6, 128), 256, 0, stream>>>(
        hg, woutT, x, nullptr, bout + (size_t)i * DIM, NTOK, DIM, DFF);
  }
  rmsnorm_kernel<0><<<NTOK, 256, 0, stream>>>(x, fnw, (float*)d_out);
}